// Round 8
// baseline (664.657 us; speedup 1.0000x reference)
//
#include <hip/hip_runtime.h>
#include <math.h>
#include <stdint.h>

#define S_LEN 2048
#define DMODEL 1024
#define NH 8
#define DK_ 128
#define DV_ 128
#define KD_ 1024
#define KCONV 4
#define CW 32     // chunk (window) length
#define NW2 64    // number of windows
// per-(w,h) bf16 block: TKh[32][128] | Qhat[32][128] | KchkT[128][32] | Tv[32][128] | N[32][32]
#define PREB_STRIDE 17408
#define TKH_OFF 0
#define QHT_OFF 4096
#define KCT_OFF 8192
#define TV_OFF 12288
#define NN_OFF 16384

typedef short bf16x8 __attribute__((ext_vector_type(8)));
typedef float f32x4 __attribute__((ext_vector_type(4)));

__device__ __forceinline__ uint16_t f2bf(float f) {  // RNE
  uint32_t u = __float_as_uint(f);
  u += 0x7FFF + ((u >> 16) & 1);
  return (uint16_t)(u >> 16);
}
__device__ __forceinline__ float bf2f(uint16_t u) {
  return __uint_as_float((uint32_t)u << 16);
}
__device__ __forceinline__ void glds16(const uint16_t* g, uint16_t* l) {
  __builtin_amdgcn_global_load_lds(
      (const __attribute__((address_space(1))) void*)g,
      (__attribute__((address_space(3))) void*)l, 16, 0, 0);
}
__device__ __forceinline__ float dot4(float4 a, float4 b) {
  return fmaf(a.w, b.w, fmaf(a.z, b.z, fmaf(a.y, b.y, a.x * b.x)));
}
__device__ __forceinline__ float4 f4add(float4 a, float4 b) {
  float4 r; r.x = a.x + b.x; r.y = a.y + b.y; r.z = a.z + b.z; r.w = a.w + b.w; return r;
}
__device__ __forceinline__ float4 f4sub(float4 a, float4 b) {
  float4 r; r.x = a.x - b.x; r.y = a.y - b.y; r.z = a.z - b.z; r.w = a.w - b.w; return r;
}
__device__ __forceinline__ float4 f4mul(float4 a, float4 b) {
  float4 r; r.x = a.x * b.x; r.y = a.y * b.y; r.z = a.z * b.z; r.w = a.w * b.w; return r;
}
__device__ __forceinline__ float4 f4s(float4 a, float s) {
  float4 r; r.x = a.x * s; r.y = a.y * s; r.z = a.z * s; r.w = a.w * s; return r;
}
__device__ __forceinline__ float4 f4expc(float4 a) {  // exp(min(a,0)) — overflow-safe
  float4 r;
  r.x = expf(fminf(a.x, 0.f)); r.y = expf(fminf(a.y, 0.f));
  r.z = expf(fminf(a.z, 0.f)); r.w = expf(fminf(a.w, 0.f));
  return r;
}
__device__ __forceinline__ float4 f4exp(float4 a) {
  float4 r; r.x = expf(a.x); r.y = expf(a.y); r.z = expf(a.z); r.w = expf(a.w); return r;
}
__device__ __forceinline__ uint4 pack8(float4 a, float4 b) {
  uint4 r;
  r.x = (uint32_t)f2bf(a.x) | ((uint32_t)f2bf(a.y) << 16);
  r.y = (uint32_t)f2bf(a.z) | ((uint32_t)f2bf(a.w) << 16);
  r.z = (uint32_t)f2bf(b.x) | ((uint32_t)f2bf(b.y) << 16);
  r.w = (uint32_t)f2bf(b.z) | ((uint32_t)f2bf(b.w) << 16);
  return r;
}
__device__ __forceinline__ uint2 pack4(f32x4 a) {
  uint2 r;
  r.x = (uint32_t)f2bf(a[0]) | ((uint32_t)f2bf(a[1]) << 16);
  r.y = (uint32_t)f2bf(a[2]) | ((uint32_t)f2bf(a[3]) << 16);
  return r;
}
union U4B8 { uint4 u; bf16x8 b; };
__device__ __forceinline__ bf16x8 u2b(uint4 u) { U4B8 x; x.u = u; return x.b; }

#define DPPADD(x, ctrl) \
  x += __int_as_float(__builtin_amdgcn_update_dpp(0, __float_as_int(x), ctrl, 0xF, 0xF, true))

// reduction over 8 consecutive lanes (xor1, xor2, half-mirror)
__device__ __forceinline__ void row8_sum2(float& a, float& b) {
  DPPADD(a, 0xB1); DPPADD(b, 0xB1);
  DPPADD(a, 0x4E); DPPADD(b, 0x4E);
  DPPADD(a, 0x141); DPPADD(b, 0x141);
}
__device__ __forceinline__ void row8_arr32(float* x) {
#pragma unroll
  for (int i = 0; i < 32; i++) DPPADD(x[i], 0xB1);
#pragma unroll
  for (int i = 0; i < 32; i++) DPPADD(x[i], 0x4E);
#pragma unroll
  for (int i = 0; i < 32; i++) DPPADD(x[i], 0x141);
}

// ---------------- fused fp32 -> bf16 cast for up to 8 tensors ----------------
struct CastArgs {
  const float* s[8];
  uint16_t* d[8];
  int n[8];
};
__global__ __launch_bounds__(256) void cast_multi(CastArgs a) {
  int i = blockIdx.y;
  int base = (blockIdx.x * 256 + threadIdx.x) * 8;
  if (base >= a.n[i]) return;
  const float4* sp = (const float4*)(a.s[i] + base);
  float4 x0 = sp[0], x1 = sp[1];
  uint4 v = pack8(x0, x1);
  *(uint4*)(a.d[i] + base) = v;
}

// ---- Wc = Wf2 @ Wf1 (fp32 math, bf16 out): collapses two-stage g-projection ----
__global__ __launch_bounds__(256) void gemm_wc(
    const float* __restrict__ A,  // Wf2 [1024,128]
    const float* __restrict__ B,  // Wf1 [128,1024]
    uint16_t* __restrict__ C) {   // Wc [1024,1024] bf16
  __shared__ float As[16][68];
  __shared__ float Bs[16][68];
  const int tid = threadIdx.x;
  const int m0 = blockIdx.y * 64, n0 = blockIdx.x * 64;
  const int tx = tid & 15, ty = tid >> 4;
  const int lk = tid & 15, lr = tid >> 4;
  const int bc = tid & 63, bkr = tid >> 6;
  float acc[4][4] = {};
  for (int k0 = 0; k0 < 128; k0 += 16) {
#pragma unroll
    for (int i = 0; i < 4; i++) {
      As[lk][lr + 16 * i] = A[(size_t)(m0 + lr + 16 * i) * 128 + k0 + lk];
      Bs[bkr + 4 * i][bc] = B[(size_t)(k0 + bkr + 4 * i) * 1024 + n0 + bc];
    }
    __syncthreads();
#pragma unroll
    for (int kk = 0; kk < 16; kk++) {
      float4 a4 = *(const float4*)&As[kk][ty * 4];
      float4 b4 = *(const float4*)&Bs[kk][tx * 4];
      float av[4] = {a4.x, a4.y, a4.z, a4.w};
      float bv[4] = {b4.x, b4.y, b4.z, b4.w};
#pragma unroll
      for (int i = 0; i < 4; i++)
#pragma unroll
        for (int jx = 0; jx < 4; jx++) acc[i][jx] = fmaf(av[i], bv[jx], acc[i][jx]);
    }
    __syncthreads();
  }
#pragma unroll
  for (int i = 0; i < 4; i++)
#pragma unroll
    for (int jx = 0; jx < 4; jx++)
      C[(size_t)(m0 + ty * 4 + i) * 1024 + n0 + tx * 4 + jx] = f2bf(acc[i][jx]);
}

// ---- pad Wb [8,1024] to bf16 [128,1024] with zero rows 8..127 ----
__global__ __launch_bounds__(256) void pad_wb(const float* __restrict__ Wb,
                                              uint16_t* __restrict__ Wbp) {
  int idx = blockIdx.x * 256 + threadIdx.x;
  if (idx >= 128 * 1024) return;
  int r = idx >> 10;
  Wbp[idx] = (r < 8) ? f2bf(Wb[idx]) : (uint16_t)0;
}

// ---------------- bf16 MFMA GEMM: C[M,N] = A[M,K] @ B[N,K]^T ----------------
struct GJobs {
  const uint16_t* A[8];
  const uint16_t* B[8];
  void* C[8];
  int N[8];
  int outbf[8];
};
__global__ __launch_bounds__(256) void gemm_mfma(GJobs j, int K) {
  const int z = blockIdx.z;
  const int N = j.N[z];
  const int n0 = blockIdx.x * 128;
  if (n0 >= N) return;
  __shared__ uint16_t Asb[128 * 32];
  __shared__ uint16_t Bsb[128 * 32];
  const uint16_t* __restrict__ A = j.A[z];
  const uint16_t* __restrict__ B = j.B[z];
  const int tid = threadIdx.x;
  const int w = tid >> 6, lane = tid & 63;
  const int m0 = blockIdx.y * 128;
  const int mw = (w & 1) * 64, nw = (w >> 1) * 64;
  const int c0 = tid, c1 = 256 + tid;
  const int r0 = c0 >> 2, cl0 = (c0 & 3) ^ ((r0 >> 2) & 3);
  const int r1 = c1 >> 2, cl1 = (c1 & 3) ^ ((r1 >> 2) & 3);
  const uint16_t* gA0 = A + (size_t)(m0 + r0) * K + cl0 * 8;
  const uint16_t* gA1 = A + (size_t)(m0 + r1) * K + cl1 * 8;
  const uint16_t* gB0 = B + (size_t)(n0 + r0) * K + cl0 * 8;
  const uint16_t* gB1 = B + (size_t)(n0 + r1) * K + cl1 * 8;
  uint16_t* lA0 = Asb + w * 512;
  uint16_t* lA1 = Asb + 2048 + w * 512;
  uint16_t* lB0 = Bsb + w * 512;
  uint16_t* lB1 = Bsb + 2048 + w * 512;

  const int l15 = lane & 15, q = lane >> 4;
  const int ccq = q ^ ((l15 >> 2) & 3);

  f32x4 acc[4][4] = {};
  for (int k0 = 0; k0 < K; k0 += 32) {
    glds16(gA0 + k0, lA0);
    glds16(gA1 + k0, lA1);
    glds16(gB0 + k0, lB0);
    glds16(gB1 + k0, lB1);
    __syncthreads();
    bf16x8 af[4], bfr[4];
#pragma unroll
    for (int i = 0; i < 4; i++)
      af[i] = *(const bf16x8*)&Asb[(mw + i * 16 + l15) * 32 + ccq * 8];
#pragma unroll
    for (int jx = 0; jx < 4; jx++)
      bfr[jx] = *(const bf16x8*)&Bsb[(nw + jx * 16 + l15) * 32 + ccq * 8];
#pragma unroll
    for (int i = 0; i < 4; i++)
#pragma unroll
      for (int jx = 0; jx < 4; jx++)
        acc[i][jx] = __builtin_amdgcn_mfma_f32_16x16x32_bf16(af[i], bfr[jx],
                                                             acc[i][jx], 0, 0, 0);
    __syncthreads();
  }
  const int obf = j.outbf[z];
#pragma unroll
  for (int i = 0; i < 4; i++) {
#pragma unroll
    for (int jx = 0; jx < 4; jx++) {
      int n = n0 + nw + jx * 16 + l15;
#pragma unroll
      for (int r = 0; r < 4; r++) {
        int m = m0 + mw + i * 16 + q * 4 + r;
        if (obf)
          ((uint16_t*)j.C[z])[(size_t)m * N + n] = f2bf(acc[i][jx][r]);
        else
          ((float*)j.C[z])[(size_t)m * N + n] = acc[i][jx][r];
      }
    }
  }
}

// -------- depthwise causal conv(K=4) + silu for q,k,v and ve; mix v ----------
// inputs are bf16 projections
__global__ __launch_bounds__(256) void conv_silu_mix(
    const uint16_t* __restrict__ qp, const uint16_t* __restrict__ kp,
    const uint16_t* __restrict__ vp, const uint16_t* __restrict__ vep,
    const float* __restrict__ wq, const float* __restrict__ wk,
    const float* __restrict__ wv, const float* __restrict__ lam,
    float* __restrict__ qc, float* __restrict__ kc, float* __restrict__ vmx) {
  int idx = blockIdx.x * 256 + threadIdx.x;
  if (idx >= S_LEN * KD_) return;
  int s = idx >> 10, d = idx & 1023;
  float aq = 0.f, ak = 0.f, av = 0.f, ae = 0.f;
#pragma unroll
  for (int i = 0; i < KCONV; i++) {
    int ss = s - (KCONV - 1) + i;
    if (ss < 0) continue;
    size_t off = (size_t)ss * KD_ + d;
    aq = fmaf(bf2f(qp[off]), wq[d * KCONV + i], aq);
    ak = fmaf(bf2f(kp[off]), wk[d * KCONV + i], ak);
    av = fmaf(bf2f(vp[off]), wv[d * KCONV + i], av);
    ae = fmaf(bf2f(vep[off]), wv[d * KCONV + i], ae);
  }
  qc[idx] = aq / (1.f + expf(-aq));
  kc[idx] = ak / (1.f + expf(-ak));
  float sv = av / (1.f + expf(-av));
  float se = ae / (1.f + expf(-ae));
  vmx[idx] = lam[0] * sv + lam[1] * se;
}

// ------ g = -exp(A_log)*softplus(graw+dt_bias), in place (raw g) ------
__global__ __launch_bounds__(256) void g_only(
    float* __restrict__ graw, const float* __restrict__ dt_bias,
    const float* __restrict__ A_log) {
  int idx = blockIdx.x * 256 + threadIdx.x;
  if (idx >= S_LEN * KD_) return;
  int c = idx & 1023;
  float xv = graw[idx] + dt_bias[c];
  float sp = (xv > 20.f) ? xv : log1pf(expf(xv));
  graw[idx] = -expf(A_log[c >> 7]) * sp;
}

// ---------------- KDA window precompute, C=32 (fully parallel) ----------------
__global__ __launch_bounds__(256) void kda_pre(
    const float* __restrict__ qc, const float* __restrict__ kc,
    const float* __restrict__ g, const float* __restrict__ vm,
    const float* __restrict__ bpre, uint16_t* __restrict__ preB,
    float* __restrict__ preF) {
  __shared__ float kls[32 * 128];
  __shared__ float Gls[32 * 128];
  __shared__ float khls[32 * 128];
  __shared__ float Mcm[32 * 36];
  __shared__ float bls[32];
  const int w = blockIdx.x >> 3, h = blockIdx.x & 7;
  const int tid = threadIdx.x;
  const int t = tid >> 3, kq = tid & 7;
  const size_t gb = (size_t)blockIdx.x * PREB_STRIDE;
  const size_t gf = (size_t)blockIdx.x * 128;

  size_t roff = (size_t)(w * CW + t) * KD_ + h * DK_ + kq * 16;
  float4 kv[4], qv[4], gv[4];
#pragma unroll
  for (int i = 0; i < 4; i++) {
    kv[i] = *(const float4*)(kc + roff + i * 4);
    qv[i] = *(const float4*)(qc + roff + i * 4);
    gv[i] = *(const float4*)(g + roff + i * 4);
  }
  if (tid < 32) {
    float b = bpre[(size_t)(w * CW + tid) * 128 + h];
    bls[tid] = 1.f / (1.f + expf(-b));
  }
  float src[32];
  if (tid >= 128) {
    int c2 = tid - 128;
#pragma unroll
    for (int t2 = 0; t2 < 32; t2++)
      src[t2] = vm[(size_t)(w * CW + t2) * KD_ + h * DV_ + c2];
  }
  float sk = 0.f, sq = 0.f;
#pragma unroll
  for (int i = 0; i < 4; i++) {
    sk += dot4(kv[i], kv[i]);
    sq += dot4(qv[i], qv[i]);
  }
  row8_sum2(sk, sq);
  float rkn = rsqrtf(sk + 1e-6f);
  float rqn = rsqrtf(sq + 1e-6f) * 0.08838834764831845f;  // * DK^-0.5
#pragma unroll
  for (int i = 0; i < 4; i++) {
    kv[i] = f4s(kv[i], rkn);
    qv[i] = f4s(qv[i], rqn);
    *(float4*)&kls[t * 128 + kq * 16 + i * 4] = kv[i];
    *(float4*)&Gls[t * 128 + kq * 16 + i * 4] = gv[i];
  }
  __syncthreads();
  float4 Ga[4] = {}, Gf[4] = {};
#pragma unroll
  for (int j = 0; j < 32; j++) {
#pragma unroll
    for (int i = 0; i < 4; i++) {
      float4 gj = *(const float4*)&Gls[j * 128 + kq * 16 + i * 4];
      Gf[i] = f4add(Gf[i], gj);
      if (j <= t) Ga[i] = f4add(Ga[i], gj);
    }
  }
  __syncthreads();
  float4 Pa[4], ea[4];
#pragma unroll
  for (int i = 0; i < 4; i++) {
    *(float4*)&Gls[t * 128 + kq * 16 + i * 4] = Ga[i];
    Pa[i] = f4exp(Ga[i]);
    ea[i] = f4exp(f4sub(Gf[i], Ga[i]));
    float4 kh = f4mul(kv[i], Pa[i]);
    *(float4*)&khls[t * 128 + kq * 16 + i * 4] = kh;
  }
  {
    float4 q0 = f4mul(qv[0], Pa[0]), q1 = f4mul(qv[1], Pa[1]);
    float4 q2 = f4mul(qv[2], Pa[2]), q3 = f4mul(qv[3], Pa[3]);
    *(uint4*)(preB + gb + QHT_OFF + t * 128 + kq * 16) = pack8(q0, q1);
    *(uint4*)(preB + gb + QHT_OFF + t * 128 + kq * 16 + 8) = pack8(q2, q3);
  }
  {
    float kk[16];
#pragma unroll
    for (int i = 0; i < 4; i++) {
      float4 kc4 = f4mul(kv[i], ea[i]);
      kk[i * 4 + 0] = kc4.x; kk[i * 4 + 1] = kc4.y;
      kk[i * 4 + 2] = kc4.z; kk[i * 4 + 3] = kc4.w;
    }
#pragma unroll
    for (int i = 0; i < 16; i++)
      preB[gb + KCT_OFF + (kq * 16 + i) * 32 + t] = f2bf(kk[i]);
  }
  if (t == 31) {
#pragma unroll
    for (int i = 0; i < 4; i++)
      *(float4*)(preF + gf + kq * 16 + i * 4) = Pa[i];
  }
  __syncthreads();
  float mp[32], np[32];
#pragma unroll
  for (int j = 0; j < 32; j++) {
    float m = 0.f, n = 0.f;
#pragma unroll
    for (int i = 0; i < 4; i++) {
      float4 kj = *(const float4*)&kls[j * 128 + kq * 16 + i * 4];
      float4 Gj = *(const float4*)&Gls[j * 128 + kq * 16 + i * 4];
      float4 e = f4expc(f4sub(Ga[i], Gj));
      float4 p = f4mul(kj, e);
      m += dot4(kv[i], p);
      n += dot4(qv[i], p);
    }
    mp[j] = (j < t) ? m : 0.f;
    np[j] = (j <= t) ? n : 0.f;
  }
  row8_arr32(mp);
  row8_arr32(np);
#pragma unroll
  for (int jj = 0; jj < 4; jj++) {
    int j = jj * 8 + kq;
    Mcm[j * 36 + t] = bls[t] * mp[j];
    preB[gb + NN_OFF + t * 32 + j] = f2bf(np[j]);
  }
  float bl[32];
#pragma unroll
  for (int i = 0; i < 8; i++) {
    float4 b4 = *(const float4*)&bls[i * 4];
    bl[i * 4 + 0] = b4.x; bl[i * 4 + 1] = b4.y;
    bl[i * 4 + 2] = b4.z; bl[i * 4 + 3] = b4.w;
  }
  if (tid < 128) {
#pragma unroll
    for (int t2 = 0; t2 < 32; t2++) src[t2] = khls[t2 * 128 + tid];
  }
  __syncthreads();
  const int c = tid;
  float acc[32];
#pragma unroll
  for (int i = 0; i < 32; i++) acc[i] = 0.f;
#pragma unroll
  for (int t2 = 0; t2 < 32; t2++) {
    float val = fmaf(bl[t2], src[t2], -acc[t2]);
    if (c < 128)
      preB[gb + TKH_OFF + t2 * 128 + c] = f2bf(val);
    else
      preB[gb + TV_OFF + t2 * 128 + (c - 128)] = f2bf(val);
#pragma unroll
    for (int t3 = t2 + 1; t3 < 32; t3++)
      acc[t3] = fmaf(Mcm[t2 * 36 + t3], val, acc[t3]);
  }
}

// ---------------- KDA scan over windows: MFMA, C=32 ----------------
__global__ __launch_bounds__(128) void kda_scan(
    const uint16_t* __restrict__ preB, const float* __restrict__ preF,
    float* __restrict__ o) {
  __shared__ uint16_t tkh[2][32 * 136];
  __shared__ uint16_t qht[2][32 * 136];
  __shared__ uint16_t sbf[16 * 136];
  __shared__ uint16_t vbf[16 * 40];
  const int h = blockIdx.x & 7, cg = blockIdx.x >> 3;
  const int tid = threadIdx.x;
  const int wv = tid >> 6, lane = tid & 63;
  const int q = lane >> 4, l15 = lane & 15;

  auto stage = [&](int w, int buf) {
    size_t gbs = (size_t)(w * 8 + h) * PREB_STRIDE;
    const uint4* gt = (const uint4*)(preB + gbs + TKH_OFF);
    const uint4* gq = (const uint4*)(preB + gbs + QHT_OFF);
    int row = lane >> 1, half = lane & 1;
    uint4 a[8], b[8];
#pragma unroll
    for (int i = 0; i < 8; i++) {
      a[i] = gt[lane * 8 + i];
      b[i] = gq[lane * 8 + i];
    }
#pragma unroll
    for (int i = 0; i < 8; i++) {
      *(uint4*)&tkh[buf][row * 136 + half * 64 + i * 8] = a[i];
      *(uint4*)&qht[buf][row * 136 + half * 64 + i * 8] = b[i];
    }
  };

  f32x4 s[8] = {};

  if (wv == 1) stage(0, 0);
  __syncthreads();

  for (int w = 0; w < NW2; w++) {
    if (wv == 1) {
      if (w + 1 < NW2) stage(w + 1, (w + 1) & 1);
    } else {
      const int buf = w & 1;
      const size_t gbs = (size_t)(w * 8 + h) * PREB_STRIDE;
      uint4 kct[8], nrg[2];
      float4 pb[8];
      float tvv[2][4];
#pragma unroll
      for (int ki = 0; ki < 8; ki++)
        kct[ki] = *(const uint4*)(preB + gbs + KCT_OFF + (16 * ki + l15) * 32 + q * 8);
#pragma unroll
      for (int tt = 0; tt < 2; tt++)
        nrg[tt] = *(const uint4*)(preB + gbs + NN_OFF + (tt * 16 + l15) * 32 + q * 8);
#pragma unroll
      for (int ki = 0; ki < 8; ki++)
        pb[ki] = *(const float4*)(preF + (size_t)(w * 8 + h) * 128 + 16 * ki + q * 4);
#pragma unroll
      for (int tt = 0; tt < 2; tt++)
#pragma unroll
        for (int r = 0; r < 4; r++)
          tvv[tt][r] = bf2f(preB[gbs + TV_OFF + (tt * 16 + q * 4 + r) * 128 + cg * 16 + l15]);
#pragma unroll
      for (int ki = 0; ki < 8; ki++)
        *(uint2*)&sbf[l15 * 136 + 16 * ki + q * 4] = pack4(s[ki]);
      f32x4 aat[2] = {}, bbt[2] = {};
#pragma unroll
      for (int kc = 0; kc < 4; kc++) {
        bf16x8 bS = *(const bf16x8*)&sbf[l15 * 136 + kc * 32 + q * 8];
#pragma unroll
        for (int tt = 0; tt < 2; tt++) {
          bf16x8 aT = *(const bf16x8*)&tkh[buf][(tt * 16 + l15) * 136 + kc * 32 + q * 8];
          bf16x8 aQ = *(const bf16x8*)&qht[buf][(tt * 16 + l15) * 136 + kc * 32 + q * 8];
          aat[tt] = __builtin_amdgcn_mfma_f32_16x16x32_bf16(aT, bS, aat[tt], 0, 0, 0);
          bbt[tt] = __builtin_amdgcn_mfma_f32_16x16x32_bf16(aQ, bS, bbt[tt], 0, 0, 0);
        }
      }
#pragma unroll
      for (int tt = 0; tt < 2; tt++) {
        f32x4 vn;
#pragma unroll
        for (int r = 0; r < 4; r++) vn[r] = tvv[tt][r] - aat[tt][r];
        *(uint2*)&vbf[l15 * 40 + tt * 16 + q * 4] = pack4(vn);
      }
      bf16x8 bV = *(const bf16x8*)&vbf[l15 * 40 + q * 8];
#pragma unroll
      for (int tt = 0; tt < 2; tt++) {
        f32x4 ot = __builtin_amdgcn_mfma_f32_16x16x32_bf16(u2b(nrg[tt]), bV,
                                                           bbt[tt], 0, 0, 0);
#pragma unroll
        for (int r = 0; r < 4; r++)
          o[(size_t)(w * CW + tt * 16 + q * 4 + r) * KD_ + h * DK_ + cg * 16 + l15] = ot[r];
      }
#pragma unroll
      for (int ki = 0; ki < 8; ki++) {
#pragma unroll
        for (int r = 0; r < 4; r++) s[ki][r] *= pb[ki][r];
        s[ki] = __builtin_amdgcn_mfma_f32_16x16x32_bf16(u2b(kct[ki]), bV, s[ki], 0, 0, 0);
      }
    }
    __syncthreads();
  }
}

// ---- FusedRMSNormGated: gate = sigmoid(g2raw + bg2) fused; bf16 out ----
__global__ __launch_bounds__(64) void gated_rmsnorm(
    const float* __restrict__ o, const float* __restrict__ g2raw,
    const float* __restrict__ bg2, const float* __restrict__ wn,
    uint16_t* __restrict__ ob) {
  size_t base = (size_t)blockIdx.x * DV_;
  int t = threadIdx.x;
  float a = o[base + t], b = o[base + t + 64];
  float ss = a * a + b * b;
#pragma unroll
  for (int off = 32; off > 0; off >>= 1) ss += __shfl_xor(ss, off);
  float r = rsqrtf(ss * (1.f / 128.f) + 1e-5f);
  int c0 = (int)((base + t) & 1023), c1 = (int)((base + t + 64) & 1023);
  float ga = 1.f / (1.f + expf(-(g2raw[base + t] + bg2[c0])));
  float gb = 1.f / (1.f + expf(-(g2raw[base + t + 64] + bg2[c1])));
  ob[base + t] = f2bf(a * r * wn[t] * ga);
  ob[base + t + 64] = f2bf(b * r * wn[t + 64] * gb);
}

extern "C" void kernel_launch(void* const* d_in, const int* in_sizes, int n_in,
                              void* d_out, int out_size, void* d_ws, size_t ws_size,
                              hipStream_t stream) {
  const float* x = (const float*)d_in[0];
  const float* ve = (const float*)d_in[1];
  const float* lam = (const float*)d_in[2];
  const float* Wq = (const float*)d_in[3];
  const float* Wk = (const float*)d_in[4];
  const float* Wv = (const float*)d_in[5];
  const float* Wo = (const float*)d_in[6];
  const float* wq_conv = (const float*)d_in[7];
  const float* wk_conv = (const float*)d_in[8];
  const float* wv_conv = (const float*)d_in[9];
  const float* Wf1 = (const float*)d_in[10];
  const float* Wf2 = (const float*)d_in[11];
  const float* Wb = (const float*)d_in[12];
  const float* A_log = (const float*)d_in[13];
  const float* dt_bias = (const float*)d_in[14];
  const float* Wg1 = (const float*)d_in[15];
  const float* Wg2 = (const float*)d_in[16];
  const float* bg2 = (const float*)d_in[17];
  const float* w_norm = (const float*)d_in[18];
  float* out = (float*)d_out;

  float* ws = (float*)d_ws;
  const size_t SZ = (size_t)S_LEN * KD_;  // 2M
  // bf16 projection buffers (each SZ u16 = SZ/2 floats)
  uint16_t* qpb = (uint16_t*)ws;
  uint16_t* kpb = (uint16_t*)(ws + SZ / 2);
  uint16_t* vpb = (uint16_t*)(ws + SZ);
  uint16_t* vepb = (uint16_t*)(ws + 3 * SZ / 2);
  float* q_c = ws + 2 * SZ;    // 4M
  float* k_c = ws + 3 * SZ;    // 6M
  float* v_mix = ws + 4 * SZ;  // 8M
  float* graw = ws + 5 * SZ;   // 10M; raw g; o_buf overlays after kda_pre
  float* o_buf = graw;
  float* g2raw = k_c;          // overlays k_c after kda_pre
  uint16_t* bws = (uint16_t*)(ws + 6 * SZ);  // 12M floats
  uint16_t* xb = bws;                            // 2M u16
  uint16_t* veb = xb + SZ;                       // 2M u16
  uint16_t* Wqb = veb + SZ;
  uint16_t* Wkb = Wqb + (size_t)KD_ * DMODEL;
  uint16_t* Wvb = Wkb + (size_t)KD_ * DMODEL;
  uint16_t* Wob = Wvb + (size_t)KD_ * DMODEL;
  uint16_t* Wg1b = Wob + (size_t)DMODEL * KD_;
  uint16_t* Wg2b = Wg1b + (size_t)DV_ * DMODEL;
  uint16_t* Wcb = Wg2b + (size_t)KD_ * DV_;      // 1M u16
  uint16_t* Wbp = Wcb + (size_t)KD_ * DMODEL;    // 128K u16
  uint16_t* g1b = Wbp + (size_t)128 * 1024;      // 256K u16
  uint16_t* ob = g1b + (size_t)S_LEN * DV_;      // 2M u16
  float* bpre2 = ws + 18 * (size_t)1024 * 1024;  // [2048,128] fp32
  float* preF = ws + (size_t)20 * 1024 * 1024;
  uint16_t* preB = (uint16_t*)(ws + (size_t)20 * 1024 * 1024 + 65536 + 64);

  dim3 blk(256);
  int ew_blocks = (S_LEN * KD_ + 255) / 256;

  CastArgs ca;
  ca.s[0] = x;   ca.d[0] = xb;   ca.n[0] = S_LEN * DMODEL;
  ca.s[1] = ve;  ca.d[1] = veb;  ca.n[1] = S_LEN * DMODEL;
  ca.s[2] = Wq;  ca.d[2] = Wqb;  ca.n[2] = KD_ * DMODEL;
  ca.s[3] = Wk;  ca.d[3] = Wkb;  ca.n[3] = KD_ * DMODEL;
  ca.s[4] = Wv;  ca.d[4] = Wvb;  ca.n[4] = KD_ * DMODEL;
  ca.s[5] = Wo;  ca.d[5] = Wob;  ca.n[5] = DMODEL * KD_;
  ca.s[6] = Wg1; ca.d[6] = Wg1b; ca.n[6] = DV_ * DMODEL;
  ca.s[7] = Wg2; ca.d[7] = Wg2b; ca.n[7] = KD_ * DV_;
  cast_multi<<<dim3(1024, 8), blk, 0, stream>>>(ca);

  gemm_wc<<<dim3(16, 16), blk, 0, stream>>>(Wf2, Wf1, Wcb);
  pad_wb<<<dim3(512), blk, 0, stream>>>(Wb, Wbp);

  // batched MFMA: q/k/v/ve projections (bf16 out), Wg1, g-path (Wc), beta (Wb)
  GJobs jq;
  jq.A[0] = xb;  jq.B[0] = Wqb;  jq.C[0] = qpb;   jq.N[0] = KD_; jq.outbf[0] = 1;
  jq.A[1] = xb;  jq.B[1] = Wkb;  jq.C[1] = kpb;   jq.N[1] = KD_; jq.outbf[1] = 1;
  jq.A[2] = xb;  jq.B[2] = Wvb;  jq.C[2] = vpb;   jq.N[2] = KD_; jq.outbf[2] = 1;
  jq.A[3] = veb; jq.B[3] = Wvb;  jq.C[3] = vepb;  jq.N[3] = KD_; jq.outbf[3] = 1;
  jq.A[4] = xb;  jq.B[4] = Wg1b; jq.C[4] = g1b;   jq.N[4] = DV_; jq.outbf[4] = 1;
  jq.A[5] = xb;  jq.B[5] = Wcb;  jq.C[5] = graw;  jq.N[5] = KD_; jq.outbf[5] = 0;
  jq.A[6] = xb;  jq.B[6] = Wbp;  jq.C[6] = bpre2; jq.N[6] = 128; jq.outbf[6] = 0;
  gemm_mfma<<<dim3(8, 16, 7), blk, 0, stream>>>(jq, DMODEL);

  conv_silu_mix<<<ew_blocks, blk, 0, stream>>>(qpb, kpb, vpb, vepb,
                                               wq_conv, wk_conv, wv_conv, lam,
                                               q_c, k_c, v_mix);

  g_only<<<ew_blocks, blk, 0, stream>>>(graw, dt_bias, A_log);

  kda_pre<<<dim3(NW2 * 8), blk, 0, stream>>>(q_c, k_c, graw, v_mix, bpre2,
                                             preB, preF);
  kda_scan<<<dim3(64), dim3(128), 0, stream>>>(preB, preF, o_buf);

  GJobs jg2;
  jg2.A[0] = g1b; jg2.B[0] = Wg2b; jg2.C[0] = g2raw; jg2.N[0] = KD_; jg2.outbf[0] = 0;
  gemm_mfma<<<dim3(8, 16, 1), blk, 0, stream>>>(jg2, DV_);

  gated_rmsnorm<<<dim3(S_LEN * NH), dim3(64), 0, stream>>>(o_buf, g2raw, bg2,
                                                           w_norm, ob);

  GJobs jo;
  jo.A[0] = ob; jo.B[0] = Wob; jo.C[0] = out; jo.N[0] = DMODEL; jo.outbf[0] = 0;
  gemm_mfma<<<dim3(8, 16, 1), blk, 0, stream>>>(jo, KD_);
}

// Round 9
// 391.550 us; speedup vs baseline: 1.6975x; 1.6975x over previous
//
#include <hip/hip_runtime.h>
#include <math.h>
#include <stdint.h>

#define S_LEN 2048
#define DMODEL 1024
#define NH 8
#define DK_ 128
#define DV_ 128
#define KD_ 1024
#define KCONV 4
#define CW 32     // chunk (window) length
#define NW2 64    // number of windows
// per-(w,h) bf16 block: TKh[32][128] | Qhat[32][128] | KchkT[128][32] | Tv[32][128] | N[32][32]
#define PREB_STRIDE 17408
#define TKH_OFF 0
#define QHT_OFF 4096
#define KCT_OFF 8192
#define TV_OFF 12288
#define NN_OFF 16384
// kda_pre LDS strides (conflict-free by construction)
#define RS 164   // row stride for kls/Gls (4t spread)
#define GS 20    // channel-group stride (20*kq mod 32 distinct for kq=0..7)

typedef short bf16x8 __attribute__((ext_vector_type(8)));
typedef float f32x4 __attribute__((ext_vector_type(4)));

__device__ __forceinline__ uint16_t f2bf(float f) {  // RNE
  uint32_t u = __float_as_uint(f);
  u += 0x7FFF + ((u >> 16) & 1);
  return (uint16_t)(u >> 16);
}
__device__ __forceinline__ float bf2f(uint16_t u) {
  return __uint_as_float((uint32_t)u << 16);
}
__device__ __forceinline__ void glds16(const uint16_t* g, uint16_t* l) {
  __builtin_amdgcn_global_load_lds(
      (const __attribute__((address_space(1))) void*)g,
      (__attribute__((address_space(3))) void*)l, 16, 0, 0);
}
__device__ __forceinline__ float dot4(float4 a, float4 b) {
  return fmaf(a.w, b.w, fmaf(a.z, b.z, fmaf(a.y, b.y, a.x * b.x)));
}
__device__ __forceinline__ float4 f4add(float4 a, float4 b) {
  float4 r; r.x = a.x + b.x; r.y = a.y + b.y; r.z = a.z + b.z; r.w = a.w + b.w; return r;
}
__device__ __forceinline__ float4 f4sub(float4 a, float4 b) {
  float4 r; r.x = a.x - b.x; r.y = a.y - b.y; r.z = a.z - b.z; r.w = a.w - b.w; return r;
}
__device__ __forceinline__ float4 f4mul(float4 a, float4 b) {
  float4 r; r.x = a.x * b.x; r.y = a.y * b.y; r.z = a.z * b.z; r.w = a.w * b.w; return r;
}
__device__ __forceinline__ float4 f4s(float4 a, float s) {
  float4 r; r.x = a.x * s; r.y = a.y * s; r.z = a.z * s; r.w = a.w * s; return r;
}
__device__ __forceinline__ float4 f4expc(float4 a) {  // exp(min(a,0)) — overflow-safe
  float4 r;
  r.x = expf(fminf(a.x, 0.f)); r.y = expf(fminf(a.y, 0.f));
  r.z = expf(fminf(a.z, 0.f)); r.w = expf(fminf(a.w, 0.f));
  return r;
}
__device__ __forceinline__ float4 f4exp(float4 a) {
  float4 r; r.x = expf(a.x); r.y = expf(a.y); r.z = expf(a.z); r.w = expf(a.w); return r;
}
__device__ __forceinline__ uint4 pack8(float4 a, float4 b) {
  uint4 r;
  r.x = (uint32_t)f2bf(a.x) | ((uint32_t)f2bf(a.y) << 16);
  r.y = (uint32_t)f2bf(a.z) | ((uint32_t)f2bf(a.w) << 16);
  r.z = (uint32_t)f2bf(b.x) | ((uint32_t)f2bf(b.y) << 16);
  r.w = (uint32_t)f2bf(b.z) | ((uint32_t)f2bf(b.w) << 16);
  return r;
}
__device__ __forceinline__ uint2 pack4(f32x4 a) {
  uint2 r;
  r.x = (uint32_t)f2bf(a[0]) | ((uint32_t)f2bf(a[1]) << 16);
  r.y = (uint32_t)f2bf(a[2]) | ((uint32_t)f2bf(a[3]) << 16);
  return r;
}
union U4B8 { uint4 u; bf16x8 b; };
__device__ __forceinline__ bf16x8 u2b(uint4 u) { U4B8 x; x.u = u; return x.b; }

#define DPPADD(x, ctrl) \
  x += __int_as_float(__builtin_amdgcn_update_dpp(0, __float_as_int(x), ctrl, 0xF, 0xF, true))

// reduction over 8 consecutive lanes (xor1, xor2, half-mirror)
__device__ __forceinline__ void row8_sum2(float& a, float& b) {
  DPPADD(a, 0xB1); DPPADD(b, 0xB1);
  DPPADD(a, 0x4E); DPPADD(b, 0x4E);
  DPPADD(a, 0x141); DPPADD(b, 0x141);
}
__device__ __forceinline__ void row8_arr8x2(float* x, float* y) {
#pragma unroll
  for (int i = 0; i < 8; i++) { DPPADD(x[i], 0xB1); DPPADD(y[i], 0xB1); }
#pragma unroll
  for (int i = 0; i < 8; i++) { DPPADD(x[i], 0x4E); DPPADD(y[i], 0x4E); }
#pragma unroll
  for (int i = 0; i < 8; i++) { DPPADD(x[i], 0x141); DPPADD(y[i], 0x141); }
}

// ---------------- fused fp32 -> bf16 cast (grid-stride) ----------------
struct CastArgs {
  const float* s[8];
  uint16_t* d[8];
  int n[8];
};
__global__ __launch_bounds__(256) void cast_multi(CastArgs a) {
  int i = blockIdx.y;
  const int step = gridDim.x * 256 * 8;
  for (int base = (blockIdx.x * 256 + threadIdx.x) * 8; base < a.n[i]; base += step) {
    const float4* sp = (const float4*)(a.s[i] + base);
    float4 x0 = sp[0], x1 = sp[1];
    *(uint4*)(a.d[i] + base) = pack8(x0, x1);
  }
}

// ---- Wc = Wf2 @ Wf1 (fp32 math, bf16 out): collapses two-stage g-projection ----
__global__ __launch_bounds__(256) void gemm_wc(
    const float* __restrict__ A,  // Wf2 [1024,128]
    const float* __restrict__ B,  // Wf1 [128,1024]
    uint16_t* __restrict__ C) {   // Wc [1024,1024] bf16
  __shared__ float As[16][68];
  __shared__ float Bs[16][68];
  const int tid = threadIdx.x;
  const int m0 = blockIdx.y * 64, n0 = blockIdx.x * 64;
  const int tx = tid & 15, ty = tid >> 4;
  const int lk = tid & 15, lr = tid >> 4;
  const int bc = tid & 63, bkr = tid >> 6;
  float acc[4][4] = {};
  for (int k0 = 0; k0 < 128; k0 += 16) {
#pragma unroll
    for (int i = 0; i < 4; i++) {
      As[lk][lr + 16 * i] = A[(size_t)(m0 + lr + 16 * i) * 128 + k0 + lk];
      Bs[bkr + 4 * i][bc] = B[(size_t)(k0 + bkr + 4 * i) * 1024 + n0 + bc];
    }
    __syncthreads();
#pragma unroll
    for (int kk = 0; kk < 16; kk++) {
      float4 a4 = *(const float4*)&As[kk][ty * 4];
      float4 b4 = *(const float4*)&Bs[kk][tx * 4];
      float av[4] = {a4.x, a4.y, a4.z, a4.w};
      float bv[4] = {b4.x, b4.y, b4.z, b4.w};
#pragma unroll
      for (int i = 0; i < 4; i++)
#pragma unroll
        for (int jx = 0; jx < 4; jx++) acc[i][jx] = fmaf(av[i], bv[jx], acc[i][jx]);
    }
    __syncthreads();
  }
#pragma unroll
  for (int i = 0; i < 4; i++)
#pragma unroll
    for (int jx = 0; jx < 4; jx++)
      C[(size_t)(m0 + ty * 4 + i) * 1024 + n0 + tx * 4 + jx] = f2bf(acc[i][jx]);
}

// ---- pad Wb [8,1024] to bf16 [128,1024] with zero rows 8..127 ----
__global__ __launch_bounds__(256) void pad_wb(const float* __restrict__ Wb,
                                              uint16_t* __restrict__ Wbp) {
  int idx = blockIdx.x * 256 + threadIdx.x;
  if (idx >= 128 * 1024) return;
  int r = idx >> 10;
  Wbp[idx] = (r < 8) ? f2bf(Wb[idx]) : (uint16_t)0;
}

// ---------------- bf16 MFMA GEMM: C[M,N] = A[M,K] @ B[N,K]^T ----------------
struct GJobs {
  const uint16_t* A[8];
  const uint16_t* B[8];
  void* C[8];
  int N[8];
  int outbf[8];
};
__global__ __launch_bounds__(256) void gemm_mfma(GJobs j, int K) {
  const int z = blockIdx.z;
  const int N = j.N[z];
  const int n0 = blockIdx.x * 128;
  if (n0 >= N) return;
  __shared__ uint16_t Asb[128 * 32];
  __shared__ uint16_t Bsb[128 * 32];
  const uint16_t* __restrict__ A = j.A[z];
  const uint16_t* __restrict__ B = j.B[z];
  const int tid = threadIdx.x;
  const int w = tid >> 6, lane = tid & 63;
  const int m0 = blockIdx.y * 128;
  const int mw = (w & 1) * 64, nw = (w >> 1) * 64;
  const int c0 = tid, c1 = 256 + tid;
  const int r0 = c0 >> 2, cl0 = (c0 & 3) ^ ((r0 >> 2) & 3);
  const int r1 = c1 >> 2, cl1 = (c1 & 3) ^ ((r1 >> 2) & 3);
  const uint16_t* gA0 = A + (size_t)(m0 + r0) * K + cl0 * 8;
  const uint16_t* gA1 = A + (size_t)(m0 + r1) * K + cl1 * 8;
  const uint16_t* gB0 = B + (size_t)(n0 + r0) * K + cl0 * 8;
  const uint16_t* gB1 = B + (size_t)(n0 + r1) * K + cl1 * 8;
  uint16_t* lA0 = Asb + w * 512;
  uint16_t* lA1 = Asb + 2048 + w * 512;
  uint16_t* lB0 = Bsb + w * 512;
  uint16_t* lB1 = Bsb + 2048 + w * 512;

  const int l15 = lane & 15, q = lane >> 4;
  const int ccq = q ^ ((l15 >> 2) & 3);

  f32x4 acc[4][4] = {};
  for (int k0 = 0; k0 < K; k0 += 32) {
    glds16(gA0 + k0, lA0);
    glds16(gA1 + k0, lA1);
    glds16(gB0 + k0, lB0);
    glds16(gB1 + k0, lB1);
    __syncthreads();
    bf16x8 af[4], bfr[4];
#pragma unroll
    for (int i = 0; i < 4; i++)
      af[i] = *(const bf16x8*)&Asb[(mw + i * 16 + l15) * 32 + ccq * 8];
#pragma unroll
    for (int jx = 0; jx < 4; jx++)
      bfr[jx] = *(const bf16x8*)&Bsb[(nw + jx * 16 + l15) * 32 + ccq * 8];
#pragma unroll
    for (int i = 0; i < 4; i++)
#pragma unroll
      for (int jx = 0; jx < 4; jx++)
        acc[i][jx] = __builtin_amdgcn_mfma_f32_16x16x32_bf16(af[i], bfr[jx],
                                                             acc[i][jx], 0, 0, 0);
    __syncthreads();
  }
  const int obf = j.outbf[z];
#pragma unroll
  for (int i = 0; i < 4; i++) {
#pragma unroll
    for (int jx = 0; jx < 4; jx++) {
      int n = n0 + nw + jx * 16 + l15;
#pragma unroll
      for (int r = 0; r < 4; r++) {
        int m = m0 + mw + i * 16 + q * 4 + r;
        if (obf)
          ((uint16_t*)j.C[z])[(size_t)m * N + n] = f2bf(acc[i][jx][r]);
        else
          ((float*)j.C[z])[(size_t)m * N + n] = acc[i][jx][r];
      }
    }
  }
}

// -------- depthwise causal conv(K=4) + silu for q,k,v and ve; mix v ----------
__global__ __launch_bounds__(256) void conv_silu_mix(
    const uint16_t* __restrict__ qp, const uint16_t* __restrict__ kp,
    const uint16_t* __restrict__ vp, const uint16_t* __restrict__ vep,
    const float* __restrict__ wq, const float* __restrict__ wk,
    const float* __restrict__ wv, const float* __restrict__ lam,
    float* __restrict__ qc, float* __restrict__ kc, float* __restrict__ vmx) {
  int idx = blockIdx.x * 256 + threadIdx.x;
  if (idx >= S_LEN * KD_) return;
  int s = idx >> 10, d = idx & 1023;
  float aq = 0.f, ak = 0.f, av = 0.f, ae = 0.f;
#pragma unroll
  for (int i = 0; i < KCONV; i++) {
    int ss = s - (KCONV - 1) + i;
    if (ss < 0) continue;
    size_t off = (size_t)ss * KD_ + d;
    aq = fmaf(bf2f(qp[off]), wq[d * KCONV + i], aq);
    ak = fmaf(bf2f(kp[off]), wk[d * KCONV + i], ak);
    av = fmaf(bf2f(vp[off]), wv[d * KCONV + i], av);
    ae = fmaf(bf2f(vep[off]), wv[d * KCONV + i], ae);
  }
  qc[idx] = aq / (1.f + expf(-aq));
  kc[idx] = ak / (1.f + expf(-ak));
  float sv = av / (1.f + expf(-av));
  float se = ae / (1.f + expf(-ae));
  vmx[idx] = lam[0] * sv + lam[1] * se;
}

// ---------------- KDA window precompute, C=32 (fully parallel) ----------------
// 512 blocks (w,h) x 256 threads (t = tid>>3, kq = tid&7 owns 16 ch).
// Fused: g = -exp(A_log[h])*softplus(graw+dt_bias); l2norm; beta sigmoid.
// Conflict-free LDS: kls/Gls stride RS=164 w/ group stride GS=20; khls 132.
// Wave-bounded loops: wave wv only processes j-blocks jb <= wv.
__global__ __launch_bounds__(256) void kda_pre(
    const float* __restrict__ qc, const float* __restrict__ kc,
    const float* __restrict__ graw, const float* __restrict__ vm,
    const float* __restrict__ bpre, const float* __restrict__ dt_bias,
    const float* __restrict__ A_log, uint16_t* __restrict__ preB,
    float* __restrict__ preF) {
  __shared__ float kls[32 * RS];    // 20992 B
  __shared__ float Gls[32 * RS];    // 20992 B
  __shared__ float khls[32 * 132];  // 16896 B
  __shared__ float Mcm[32 * 36];    // 4608 B
  __shared__ float bls[32];
  const int w = blockIdx.x >> 3, h = blockIdx.x & 7;
  const int tid = threadIdx.x;
  const int t = tid >> 3, kq = tid & 7;
  const int wv = tid >> 6;
  const size_t gb = (size_t)blockIdx.x * PREB_STRIDE;
  const size_t gf = (size_t)blockIdx.x * 128;

  size_t roff = (size_t)(w * CW + t) * KD_ + h * DK_ + kq * 16;
  float4 kv[4], qv[4], gv[4], dtb[4];
#pragma unroll
  for (int i = 0; i < 4; i++) {
    kv[i] = *(const float4*)(kc + roff + i * 4);
    qv[i] = *(const float4*)(qc + roff + i * 4);
    gv[i] = *(const float4*)(graw + roff + i * 4);
    dtb[i] = *(const float4*)(dt_bias + h * DK_ + kq * 16 + i * 4);
  }
  const float Ahead = expf(A_log[h]);
  if (tid < 32) {
    float b = bpre[(size_t)(w * CW + tid) * 128 + h];
    bls[tid] = 1.f / (1.f + expf(-b));
  }
  float src[32];
  if (tid >= 128) {
    int c2 = tid - 128;
#pragma unroll
    for (int t2 = 0; t2 < 32; t2++)
      src[t2] = vm[(size_t)(w * CW + t2) * KD_ + h * DV_ + c2];
  }
  // fused g transform: g = -A * softplus(graw + dt_bias)
#pragma unroll
  for (int i = 0; i < 4; i++) {
    float vsp[4];
    float xin[4] = {gv[i].x + dtb[i].x, gv[i].y + dtb[i].y,
                    gv[i].z + dtb[i].z, gv[i].w + dtb[i].w};
#pragma unroll
    for (int e = 0; e < 4; e++)
      vsp[e] = (xin[e] > 20.f) ? xin[e] : log1pf(expf(xin[e]));
    gv[i].x = -Ahead * vsp[0]; gv[i].y = -Ahead * vsp[1];
    gv[i].z = -Ahead * vsp[2]; gv[i].w = -Ahead * vsp[3];
  }
  // fused l2norm (16-ch partial + 8-lane reduce)
  float sk = 0.f, sq = 0.f;
#pragma unroll
  for (int i = 0; i < 4; i++) {
    sk += dot4(kv[i], kv[i]);
    sq += dot4(qv[i], qv[i]);
  }
  row8_sum2(sk, sq);
  float rkn = rsqrtf(sk + 1e-6f);
  float rqn = rsqrtf(sq + 1e-6f) * 0.08838834764831845f;  // * DK^-0.5
#pragma unroll
  for (int i = 0; i < 4; i++) {
    kv[i] = f4s(kv[i], rkn);
    qv[i] = f4s(qv[i], rqn);
    *(float4*)&kls[t * RS + kq * GS + i * 4] = kv[i];
    *(float4*)&Gls[t * RS + kq * GS + i * 4] = gv[i];
  }
  __syncthreads();
  // prefix-sum Ga over j <= t (wave-bounded blocks of 8)
  float4 Ga[4] = {};
#pragma unroll
  for (int jb = 0; jb < 4; jb++) {
    if (jb <= wv) {
#pragma unroll
      for (int jj = 0; jj < 8; jj++) {
        int j = jb * 8 + jj;
        bool inc = (jb < wv) || (j <= t);
#pragma unroll
        for (int i = 0; i < 4; i++) {
          float4 gj = *(const float4*)&Gls[j * RS + kq * GS + i * 4];
          if (inc) Ga[i] = f4add(Ga[i], gj);
        }
      }
    }
  }
  __syncthreads();  // all raw-g reads done
  float4 Pa[4];
#pragma unroll
  for (int i = 0; i < 4; i++) {
    *(float4*)&Gls[t * RS + kq * GS + i * 4] = Ga[i];  // overwrite w/ cumsum
    Pa[i] = f4exp(Ga[i]);
    float4 kh = f4mul(kv[i], Pa[i]);
    *(float4*)&khls[t * 132 + kq * 16 + i * 4] = kh;
  }
  {
    float4 q0 = f4mul(qv[0], Pa[0]), q1 = f4mul(qv[1], Pa[1]);
    float4 q2 = f4mul(qv[2], Pa[2]), q3 = f4mul(qv[3], Pa[3]);
    *(uint4*)(preB + gb + QHT_OFF + t * 128 + kq * 16) = pack8(q0, q1);
    *(uint4*)(preB + gb + QHT_OFF + t * 128 + kq * 16 + 8) = pack8(q2, q3);
  }
  if (t == 31) {
#pragma unroll
    for (int i = 0; i < 4; i++)
      *(float4*)(preF + gf + kq * 16 + i * 4) = Pa[i];
  }
  __syncthreads();  // cumsum visible
  // Gf = cumsum row 31; Kchk = k * exp(Gf - Ga)
#pragma unroll
  for (int i = 0; i < 4; i++) {
    float4 Gfi = *(const float4*)&Gls[31 * RS + kq * GS + i * 4];
    float4 ea = f4expc(f4sub(Gfi, Ga[i]));
    float4 kc4 = f4mul(kv[i], ea);
    float kk[4] = {kc4.x, kc4.y, kc4.z, kc4.w};
#pragma unroll
    for (int e = 0; e < 4; e++)
      preB[gb + KCT_OFF + (kq * 16 + i * 4 + e) * 32 + t] = f2bf(kk[e]);
  }
  // M (strict lower, beta-folded -> LDS) and N (j<=t -> global bf16)
#pragma unroll
  for (int jb = 0; jb < 4; jb++) {
    if (jb <= wv) {
      float mp8[8], np8[8];
#pragma unroll
      for (int jj = 0; jj < 8; jj++) {
        int j = jb * 8 + jj;
        float m = 0.f, n = 0.f;
#pragma unroll
        for (int i = 0; i < 4; i++) {
          float4 kj = *(const float4*)&kls[j * RS + kq * GS + i * 4];
          float4 Gj = *(const float4*)&Gls[j * RS + kq * GS + i * 4];
          float4 e = f4expc(f4sub(Ga[i], Gj));
          float4 p = f4mul(kj, e);
          m += dot4(kv[i], p);
          n += dot4(qv[i], p);
        }
        mp8[jj] = (j < t) ? m : 0.f;
        np8[jj] = (j <= t) ? n : 0.f;
      }
      row8_arr8x2(mp8, np8);
#pragma unroll
      for (int jj = 0; jj < 8; jj++) {
        if (kq == jj) {
          int j = jb * 8 + jj;
          Mcm[j * 36 + t] = bls[t] * mp8[jj];
          preB[gb + NN_OFF + t * 32 + j] = f2bf(np8[jj]);
        }
      }
    } else {
      // zero N entries for j > t in skipped blocks (one per lane)
      preB[gb + NN_OFF + t * 32 + jb * 8 + kq] = 0;
    }
  }
  // fwd-sub sources
  float bl[32];
#pragma unroll
  for (int i = 0; i < 8; i++) {
    float4 b4 = *(const float4*)&bls[i * 4];
    bl[i * 4 + 0] = b4.x; bl[i * 4 + 1] = b4.y;
    bl[i * 4 + 2] = b4.z; bl[i * 4 + 3] = b4.w;
  }
  if (tid < 128) {
#pragma unroll
    for (int t2 = 0; t2 < 32; t2++) src[t2] = khls[t2 * 132 + tid];
  }
  __syncthreads();  // Mcm ready
  // forward substitution: one column per thread (c<128: TKh, c>=128: Tv)
  const int c = tid;
  float acc[32];
#pragma unroll
  for (int i = 0; i < 32; i++) acc[i] = 0.f;
#pragma unroll
  for (int t2 = 0; t2 < 32; t2++) {
    float val = fmaf(bl[t2], src[t2], -acc[t2]);
    if (c < 128)
      preB[gb + TKH_OFF + t2 * 128 + c] = f2bf(val);
    else
      preB[gb + TV_OFF + t2 * 128 + (c - 128)] = f2bf(val);
#pragma unroll
    for (int t3 = t2 + 1; t3 < 32; t3++)
      acc[t3] = fmaf(Mcm[t2 * 36 + t3], val, acc[t3]);
  }
}

// ---------------- KDA scan over windows: MFMA, C=32 ----------------
__global__ __launch_bounds__(128) void kda_scan(
    const uint16_t* __restrict__ preB, const float* __restrict__ preF,
    float* __restrict__ o) {
  __shared__ uint16_t tkh[2][32 * 136];
  __shared__ uint16_t qht[2][32 * 136];
  __shared__ uint16_t sbf[16 * 136];
  __shared__ uint16_t vbf[16 * 40];
  const int h = blockIdx.x & 7, cg = blockIdx.x >> 3;
  const int tid = threadIdx.x;
  const int wv = tid >> 6, lane = tid & 63;
  const int q = lane >> 4, l15 = lane & 15;

  auto stage = [&](int w, int buf) {
    size_t gbs = (size_t)(w * 8 + h) * PREB_STRIDE;
    const uint4* gt = (const uint4*)(preB + gbs + TKH_OFF);
    const uint4* gq = (const uint4*)(preB + gbs + QHT_OFF);
    int row = lane >> 1, half = lane & 1;
    uint4 a[8], b[8];
#pragma unroll
    for (int i = 0; i < 8; i++) {
      a[i] = gt[lane * 8 + i];
      b[i] = gq[lane * 8 + i];
    }
#pragma unroll
    for (int i = 0; i < 8; i++) {
      *(uint4*)&tkh[buf][row * 136 + half * 64 + i * 8] = a[i];
      *(uint4*)&qht[buf][row * 136 + half * 64 + i * 8] = b[i];
    }
  };

  f32x4 s[8] = {};

  if (wv == 1) stage(0, 0);
  __syncthreads();

  for (int w = 0; w < NW2; w++) {
    if (wv == 1) {
      if (w + 1 < NW2) stage(w + 1, (w + 1) & 1);
    } else {
      const int buf = w & 1;
      const size_t gbs = (size_t)(w * 8 + h) * PREB_STRIDE;
      uint4 kct[8], nrg[2];
      float4 pb[8];
      float tvv[2][4];
#pragma unroll
      for (int ki = 0; ki < 8; ki++)
        kct[ki] = *(const uint4*)(preB + gbs + KCT_OFF + (16 * ki + l15) * 32 + q * 8);
#pragma unroll
      for (int tt = 0; tt < 2; tt++)
        nrg[tt] = *(const uint4*)(preB + gbs + NN_OFF + (tt * 16 + l15) * 32 + q * 8);
#pragma unroll
      for (int ki = 0; ki < 8; ki++)
        pb[ki] = *(const float4*)(preF + (size_t)(w * 8 + h) * 128 + 16 * ki + q * 4);
#pragma unroll
      for (int tt = 0; tt < 2; tt++)
#pragma unroll
        for (int r = 0; r < 4; r++)
          tvv[tt][r] = bf2f(preB[gbs + TV_OFF + (tt * 16 + q * 4 + r) * 128 + cg * 16 + l15]);
#pragma unroll
      for (int ki = 0; ki < 8; ki++)
        *(uint2*)&sbf[l15 * 136 + 16 * ki + q * 4] = pack4(s[ki]);
      f32x4 aat[2] = {}, bbt[2] = {};
#pragma unroll
      for (int kc = 0; kc < 4; kc++) {
        bf16x8 bS = *(const bf16x8*)&sbf[l15 * 136 + kc * 32 + q * 8];
#pragma unroll
        for (int tt = 0; tt < 2; tt++) {
          bf16x8 aT = *(const bf16x8*)&tkh[buf][(tt * 16 + l15) * 136 + kc * 32 + q * 8];
          bf16x8 aQ = *(const bf16x8*)&qht[buf][(tt * 16 + l15) * 136 + kc * 32 + q * 8];
          aat[tt] = __builtin_amdgcn_mfma_f32_16x16x32_bf16(aT, bS, aat[tt], 0, 0, 0);
          bbt[tt] = __builtin_amdgcn_mfma_f32_16x16x32_bf16(aQ, bS, bbt[tt], 0, 0, 0);
        }
      }
#pragma unroll
      for (int tt = 0; tt < 2; tt++) {
        f32x4 vn;
#pragma unroll
        for (int r = 0; r < 4; r++) vn[r] = tvv[tt][r] - aat[tt][r];
        *(uint2*)&vbf[l15 * 40 + tt * 16 + q * 4] = pack4(vn);
      }
      bf16x8 bV = *(const bf16x8*)&vbf[l15 * 40 + q * 8];
#pragma unroll
      for (int tt = 0; tt < 2; tt++) {
        f32x4 ot = __builtin_amdgcn_mfma_f32_16x16x32_bf16(u2b(nrg[tt]), bV,
                                                           bbt[tt], 0, 0, 0);
#pragma unroll
        for (int r = 0; r < 4; r++)
          o[(size_t)(w * CW + tt * 16 + q * 4 + r) * KD_ + h * DK_ + cg * 16 + l15] = ot[r];
      }
#pragma unroll
      for (int ki = 0; ki < 8; ki++) {
#pragma unroll
        for (int r = 0; r < 4; r++) s[ki][r] *= pb[ki][r];
        s[ki] = __builtin_amdgcn_mfma_f32_16x16x32_bf16(u2b(kct[ki]), bV, s[ki], 0, 0, 0);
      }
    }
    __syncthreads();
  }
}

// ---- FusedRMSNormGated: gate = sigmoid(g2raw + bg2) fused; bf16 out ----
__global__ __launch_bounds__(64) void gated_rmsnorm(
    const float* __restrict__ o, const float* __restrict__ g2raw,
    const float* __restrict__ bg2, const float* __restrict__ wn,
    uint16_t* __restrict__ ob) {
  size_t base = (size_t)blockIdx.x * DV_;
  int t = threadIdx.x;
  float a = o[base + t], b = o[base + t + 64];
  float ss = a * a + b * b;
#pragma unroll
  for (int off = 32; off > 0; off >>= 1) ss += __shfl_xor(ss, off);
  float r = rsqrtf(ss * (1.f / 128.f) + 1e-5f);
  int c0 = (int)((base + t) & 1023), c1 = (int)((base + t + 64) & 1023);
  float ga = 1.f / (1.f + expf(-(g2raw[base + t] + bg2[c0])));
  float gb = 1.f / (1.f + expf(-(g2raw[base + t + 64] + bg2[c1])));
  ob[base + t] = f2bf(a * r * wn[t] * ga);
  ob[base + t + 64] = f2bf(b * r * wn[t + 64] * gb);
}

extern "C" void kernel_launch(void* const* d_in, const int* in_sizes, int n_in,
                              void* d_out, int out_size, void* d_ws, size_t ws_size,
                              hipStream_t stream) {
  const float* x = (const float*)d_in[0];
  const float* ve = (const float*)d_in[1];
  const float* lam = (const float*)d_in[2];
  const float* Wq = (const float*)d_in[3];
  const float* Wk = (const float*)d_in[4];
  const float* Wv = (const float*)d_in[5];
  const float* Wo = (const float*)d_in[6];
  const float* wq_conv = (const float*)d_in[7];
  const float* wk_conv = (const float*)d_in[8];
  const float* wv_conv = (const float*)d_in[9];
  const float* Wf1 = (const float*)d_in[10];
  const float* Wf2 = (const float*)d_in[11];
  const float* Wb = (const float*)d_in[12];
  const float* A_log = (const float*)d_in[13];
  const float* dt_bias = (const float*)d_in[14];
  const float* Wg1 = (const float*)d_in[15];
  const float* Wg2 = (const float*)d_in[16];
  const float* bg2 = (const float*)d_in[17];
  const float* w_norm = (const float*)d_in[18];
  float* out = (float*)d_out;

  float* ws = (float*)d_ws;
  const size_t SZ = (size_t)S_LEN * KD_;  // 2M
  uint16_t* qpb = (uint16_t*)ws;
  uint16_t* kpb = (uint16_t*)(ws + SZ / 2);
  uint16_t* vpb = (uint16_t*)(ws + SZ);
  uint16_t* vepb = (uint16_t*)(ws + 3 * SZ / 2);
  float* q_c = ws + 2 * SZ;    // 4M
  float* k_c = ws + 3 * SZ;    // 6M
  float* v_mix = ws + 4 * SZ;  // 8M
  float* graw = ws + 5 * SZ;   // 10M; raw x@Wc^T; o_buf overlays after kda_pre
  float* o_buf = graw;
  float* g2raw = k_c;          // overlays k_c after kda_pre
  uint16_t* bws = (uint16_t*)(ws + 6 * SZ);  // 12M floats
  uint16_t* xb = bws;
  uint16_t* veb = xb + SZ;
  uint16_t* Wqb = veb + SZ;
  uint16_t* Wkb = Wqb + (size_t)KD_ * DMODEL;
  uint16_t* Wvb = Wkb + (size_t)KD_ * DMODEL;
  uint16_t* Wob = Wvb + (size_t)KD_ * DMODEL;
  uint16_t* Wg1b = Wob + (size_t)DMODEL * KD_;
  uint16_t* Wg2b = Wg1b + (size_t)DV_ * DMODEL;
  uint16_t* Wcb = Wg2b + (size_t)KD_ * DV_;
  uint16_t* Wbp = Wcb + (size_t)KD_ * DMODEL;
  uint16_t* g1b = Wbp + (size_t)128 * 1024;
  uint16_t* ob = g1b + (size_t)S_LEN * DV_;
  float* bpre2 = ws + 18 * (size_t)1024 * 1024;  // [2048,128] fp32
  float* preF = ws + (size_t)20 * 1024 * 1024;
  uint16_t* preB = (uint16_t*)(ws + (size_t)20 * 1024 * 1024 + 65536 + 64);

  dim3 blk(256);
  int ew_blocks = (S_LEN * KD_ + 255) / 256;

  CastArgs ca;
  ca.s[0] = x;   ca.d[0] = xb;   ca.n[0] = S_LEN * DMODEL;
  ca.s[1] = ve;  ca.d[1] = veb;  ca.n[1] = S_LEN * DMODEL;
  ca.s[2] = Wq;  ca.d[2] = Wqb;  ca.n[2] = KD_ * DMODEL;
  ca.s[3] = Wk;  ca.d[3] = Wkb;  ca.n[3] = KD_ * DMODEL;
  ca.s[4] = Wv;  ca.d[4] = Wvb;  ca.n[4] = KD_ * DMODEL;
  ca.s[5] = Wo;  ca.d[5] = Wob;  ca.n[5] = DMODEL * KD_;
  ca.s[6] = Wg1; ca.d[6] = Wg1b; ca.n[6] = DV_ * DMODEL;
  ca.s[7] = Wg2; ca.d[7] = Wg2b; ca.n[7] = KD_ * DV_;
  cast_multi<<<dim3(256, 8), blk, 0, stream>>>(ca);

  gemm_wc<<<dim3(16, 16), blk, 0, stream>>>(Wf2, Wf1, Wcb);
  pad_wb<<<dim3(512), blk, 0, stream>>>(Wb, Wbp);

  GJobs jq;
  jq.A[0] = xb;  jq.B[0] = Wqb;  jq.C[0] = qpb;   jq.N[0] = KD_; jq.outbf[0] = 1;
  jq.A[1] = xb;  jq.B[1] = Wkb;  jq.C[1] = kpb;   jq.N[1] = KD_; jq.outbf[1] = 1;
  jq.A[2] = xb;  jq.B[2] = Wvb;  jq.C[2] = vpb;   jq.N[2] = KD_; jq.outbf[2] = 1;
  jq.A[3] = veb; jq.B[3] = Wvb;  jq.C[3] = vepb;  jq.N[3] = KD_; jq.outbf[3] = 1;
  jq.A[4] = xb;  jq.B[4] = Wg1b; jq.C[4] = g1b;   jq.N[4] = DV_; jq.outbf[4] = 1;
  jq.A[5] = xb;  jq.B[5] = Wcb;  jq.C[5] = graw;  jq.N[5] = KD_; jq.outbf[5] = 0;
  jq.A[6] = xb;  jq.B[6] = Wbp;  jq.C[6] = bpre2; jq.N[6] = 128; jq.outbf[6] = 0;
  gemm_mfma<<<dim3(8, 16, 7), blk, 0, stream>>>(jq, DMODEL);

  conv_silu_mix<<<ew_blocks, blk, 0, stream>>>(qpb, kpb, vpb, vepb,
                                               wq_conv, wk_conv, wv_conv, lam,
                                               q_c, k_c, v_mix);

  kda_pre<<<dim3(NW2 * 8), blk, 0, stream>>>(q_c, k_c, graw, v_mix, bpre2,
                                             dt_bias, A_log, preB, preF);
  kda_scan<<<dim3(64), dim3(128), 0, stream>>>(preB, preF, o_buf);

  GJobs jg2;
  jg2.A[0] = g1b; jg2.B[0] = Wg2b; jg2.C[0] = g2raw; jg2.N[0] = KD_; jg2.outbf[0] = 0;
  gemm_mfma<<<dim3(8, 16, 1), blk, 0, stream>>>(jg2, DV_);

  gated_rmsnorm<<<dim3(S_LEN * NH), dim3(64), 0, stream>>>(o_buf, g2raw, bg2,
                                                           w_norm, ob);

  GJobs jo;
  jo.A[0] = ob; jo.B[0] = Wob; jo.C[0] = out; jo.N[0] = DMODEL; jo.outbf[0] = 0;
  gemm_mfma<<<dim3(8, 16, 1), blk, 0, stream>>>(jo, KD_);
}